// Round 9
// baseline (1699.234 us; speedup 1.0000x reference)
//
#include <hip/hip_runtime.h>

typedef _Float16 f16;
typedef f16 f16x8 __attribute__((ext_vector_type(8)));
typedef float f32x4 __attribute__((ext_vector_type(4)));

#define EPSBN 1e-3f

// async global->LDS, 16B per lane; lds dest is wave-uniform base (+lane*16 by HW)
__device__ __forceinline__ void stage16(const f16* g, const f16* l) {
    __builtin_amdgcn_global_load_lds(
        (const __attribute__((address_space(1))) unsigned int*)g,
        (__attribute__((address_space(3))) unsigned int*)l,
        16, 0, 0);
}

// ---------------- prep: fold BN into weights, transpose to [N][K] f16, cvt inputs ----------------
__global__ __launch_bounds__(256) void prep_kernel(
    const float* __restrict__ inputs,
    const float* __restrict__ att_w, const float* __restrict__ att_gamma,
    const float* __restrict__ att_beta, const float* __restrict__ att_mean,
    const float* __restrict__ att_var,
    const float* __restrict__ proj_w,
    const float* __restrict__ glu_w, const float* __restrict__ glu_gamma,
    const float* __restrict__ glu_beta, const float* __restrict__ glu_mean,
    const float* __restrict__ glu_var,
    const float* __restrict__ out_w,
    f16* __restrict__ inputs16,
    f16* __restrict__ watt, f16* __restrict__ wproj, f16* __restrict__ wglu,
    f16* __restrict__ wout, float* __restrict__ t_att, float* __restrict__ t_glu)
{
    int tid = blockIdx.x * blockDim.x + threadIdx.x;
    int nth = gridDim.x * blockDim.x;
    for (int i = tid; i < 65536 * 512 / 8; i += nth) {
        float4 u0 = ((const float4*)inputs)[i * 2];
        float4 u1 = ((const float4*)inputs)[i * 2 + 1];
        f16x8 h = {(f16)u0.x, (f16)u0.y, (f16)u0.z, (f16)u0.w,
                   (f16)u1.x, (f16)u1.y, (f16)u1.z, (f16)u1.w};
        ((f16x8*)inputs16)[i] = h;
    }
    for (int i = tid; i < 512 * 512; i += nth) {
        int n = i >> 9, k = i & 511;
        float s = att_gamma[n] * rsqrtf(att_var[n] + EPSBN);
        watt[i] = (f16)(att_w[k * 512 + n] * s);
    }
    for (int i = tid; i < 256 * 512; i += nth) {
        int n = i >> 9, k = i & 511;
        wproj[i] = (f16)(proj_w[k * 256 + n]);
    }
    for (int i = tid; i < 4 * 512 * 256; i += nth) {
        int g = i >> 17, r = i & 131071;
        int n = r >> 8, k = r & 255;
        int c = (n & 1) ? 256 + (n >> 1) : (n >> 1);
        float s = glu_gamma[g * 512 + c] * rsqrtf(glu_var[g * 512 + c] + EPSBN);
        wglu[i] = (f16)(glu_w[g * 131072 + k * 512 + c] * s);
    }
    for (int i = tid; i < 128 * 256; i += nth) {
        int n = i >> 8, k = i & 255;
        wout[i] = (f16)(out_w[k * 128 + n]);
    }
    for (int n = tid; n < 512; n += nth) {
        float s = att_gamma[n] * rsqrtf(att_var[n] + EPSBN);
        t_att[n] = att_beta[n] - att_mean[n] * s;
    }
    for (int i = tid; i < 4 * 512; i += nth) {
        int g = i >> 9, n = i & 511;
        int c = (n & 1) ? 256 + (n >> 1) : (n >> 1);
        float s = glu_gamma[g * 512 + c] * rsqrtf(glu_var[g * 512 + c] + EPSBN);
        t_glu[i] = glu_beta[g * 512 + c] - glu_mean[g * 512 + c] * s;
    }
}

// ---------------- fused att GEMM + register sparsemax (37KB LDS -> 4 blocks/CU) ----------------
// 256 threads / 4 waves; block tile 64 rows x 512 cols; wave w: rows w*16..+16, all 512 cols.
// acc[n][j]: row = w*16 + lq*4 + j, col = n*16 + lr. Row r lives on 16 lanes (lq const).
__global__ __launch_bounds__(256, 4) void att_sparsemax_kernel(
    const f16* __restrict__ in16, const f16* __restrict__ watt,
    const float* __restrict__ t_att, const float* __restrict__ priors,
    float* __restrict__ maskout, float* __restrict__ npout,
    f16* __restrict__ masked)
{
    __shared__ f16 Abuf[64 * 32];     // 4KB  A staging
    __shared__ f16 Bbuf[64 * 264];    // 33.8KB: B staging (first 32KB) / mask repack [64][264]
    const int rBase = blockIdx.x * 64;
    const int tid = threadIdx.x;
    const int lane = tid & 63;
    const int w = tid >> 6;
    const int lr = lane & 15, lq = lane >> 4;

    f32x4 acc[32];
#pragma unroll
    for (int n = 0; n < 32; n++) acc[n] = (f32x4){0.f, 0.f, 0.f, 0.f};

    for (int k0 = 0; k0 < 512; k0 += 32) {
        __syncthreads();
        {   // A tile 64x32 f16 = 256 chunks of 16B; chunk c: row=c>>2, kc=c&3
            const int c = w * 64 + lane;
            stage16(in16 + (size_t)(rBase + (c >> 2)) * 512 + k0 + (c & 3) * 8,
                    Abuf + w * 512);
        }
#pragma unroll
        for (int i = 0; i < 8; i++) {  // B tile 512x32 f16 = 2048 chunks, 8 issues/wave
            const int g = w * 8 + i;
            const int c = g * 64 + lane;
            stage16(watt + (size_t)(c >> 2) * 512 + k0 + (c & 3) * 8,
                    Bbuf + g * 512);
        }
        __syncthreads();
        f16x8 af = *(const f16x8*)&Abuf[(w * 16 + lr) * 32 + lq * 8];
#pragma unroll
        for (int n = 0; n < 32; n++) {
            f16x8 bf = *(const f16x8*)&Bbuf[(n * 16 + lr) * 32 + lq * 8];
            acc[n] = __builtin_amdgcn_mfma_f32_16x16x32_f16(af, bf, acc[n], 0, 0, 0);
        }
    }

    // phase 1: z = (acc + t) * priors, f32 in regs
#pragma unroll
    for (int n = 0; n < 32; n++) {
        const float t = t_att[n * 16 + lr];
        const size_t pb = (size_t)(rBase + w * 16 + lq * 4) * 512 + n * 16 + lr;
#pragma unroll
        for (int j = 0; j < 4; j++)
            acc[n][j] = (acc[n][j] + t) * priors[pb + (size_t)j * 512];
    }

    // phase 2: per-row sparsemax over 16-lane groups (4 rows per group via j)
    float lo[4], hi[4];
#pragma unroll
    for (int j = 0; j < 4; j++) {
        float m = acc[0][j];
#pragma unroll
        for (int n = 1; n < 32; n++) m = fmaxf(m, acc[n][j]);
#pragma unroll
        for (int d = 1; d < 16; d <<= 1) m = fmaxf(m, __shfl_xor(m, d, 64));
        lo[j] = m - 1.f; hi[j] = m;
    }
    for (int it = 0; it < 10; ++it) {
#pragma unroll
        for (int j = 0; j < 4; j++) {
            const float tau = 0.5f * (lo[j] + hi[j]);
            float s = 0.f;
#pragma unroll
            for (int n = 0; n < 32; n++) s += fmaxf(acc[n][j] - tau, 0.f);
#pragma unroll
            for (int d = 1; d < 16; d <<= 1) s += __shfl_xor(s, d, 64);
            if (s >= 1.f) lo[j] = tau; else hi[j] = tau;
        }
    }
    float tau[4];
#pragma unroll
    for (int j = 0; j < 4; j++) {
        float cnt = 0.f, sm = 0.f;
#pragma unroll
        for (int n = 0; n < 32; n++) {
            if (acc[n][j] > lo[j]) { cnt += 1.f; sm += acc[n][j]; }
        }
#pragma unroll
        for (int d = 1; d < 16; d <<= 1) {
            cnt += __shfl_xor(cnt, d, 64);
            sm += __shfl_xor(sm, d, 64);
        }
        tau[j] = (sm - 1.f) / cnt;
    }

    // phase 3: mask into acc; write mask, np (16 lanes x f32 = 64B sectors)
#pragma unroll
    for (int n = 0; n < 32; n++) {
        const size_t pb = (size_t)(rBase + w * 16 + lq * 4) * 512 + n * 16 + lr;
#pragma unroll
        for (int j = 0; j < 4; j++) {
            const float mk = fmaxf(acc[n][j] - tau[j], 0.f);
            acc[n][j] = mk;
            maskout[pb + (size_t)j * 512] = mk;
            npout[pb + (size_t)j * 512] = priors[pb + (size_t)j * 512] * (1.f - mk);
        }
    }

    // phase 4: masked = mask * inputs, via repack in two 256-col halves (reuses Bbuf)
#pragma unroll 1
    for (int h = 0; h < 2; h++) {
        __syncthreads();  // previous half's reads / K-loop reads done
#pragma unroll
        for (int n = 16 * h; n < 16 * h + 16; n++) {
            const int colh = (n - 16 * h) * 16 + lr;
#pragma unroll
            for (int j = 0; j < 4; j++)
                Bbuf[(w * 16 + lq * 4 + j) * 264 + colh] = (f16)acc[n][j];
        }
        __syncthreads();
#pragma unroll
        for (int i = 0; i < 8; i++) {  // 64x256 f16 = 2048 16B-chunks / 256 thr
            const int c = i * 256 + tid;
            const int row = c >> 5, col8 = (c & 31) * 8;
            f16x8 mv = *(const f16x8*)&Bbuf[row * 264 + col8];
            const size_t gb = (size_t)(rBase + row) * 512 + h * 256 + col8;
            f16x8 xv = *(const f16x8*)(in16 + gb);
            *(f16x8*)(masked + gb) = mv * xv;
        }
    }
}

// ---------------- mega-fused feature chain: proj + 4x GLU + out ----------------
// 512 threads / 8 waves; 128 rows/block; x in LDS [128][264] (in-place GLU update).
// ALL MFMA operands from LDS; B staged per K-step via global_load_lds (L2-resident weights).
__global__ __launch_bounds__(512, 2) void chain_kernel(
    const f16* __restrict__ masked, const f16* __restrict__ wproj,
    const float* __restrict__ proj_b, const f16* __restrict__ wglu,
    const float* __restrict__ t_glu, const f16* __restrict__ wout,
    const float* __restrict__ out_b, float* __restrict__ outp)
{
    __shared__ f16 X[128 * 264];   // 67.6KB x buffer (pad 8 -> conflict-free stride)
    __shared__ f16 Bs[512 * 32];   // 32KB B staging (GLU max; proj 256x32, out 128x32)
    __shared__ f16 As[128 * 32];   // 8KB A staging (proj only)
    const int rBase = blockIdx.x * 128;
    const int tid = threadIdx.x;
    const int lane = tid & 63;
    const int w = tid >> 6;        // 0..7
    const int lr = lane & 15, lq = lane >> 4;

    // ---- proj: C 128x256, wave cols [w*32,+32), K=512; A=masked staged, B=wproj staged ----
    {
        f32x4 acc[8][2];
#pragma unroll
        for (int m = 0; m < 8; m++)
#pragma unroll
            for (int n = 0; n < 2; n++) acc[m][n] = (f32x4){0.f, 0.f, 0.f, 0.f};
        for (int k0 = 0; k0 < 512; k0 += 32) {
            __syncthreads();
            {   // A tile 128x32 = 512 chunks; 1/thread; c = w*64+lane = tid
                const int c = tid;
                stage16(masked + (size_t)(rBase + (c >> 2)) * 512 + k0 + (c & 3) * 8,
                        As + w * 512);
            }
#pragma unroll
            for (int i = 0; i < 2; i++) {  // B tile 256x32 = 1024 chunks; 2/wave
                const int g = w * 2 + i;
                const int c = g * 64 + lane;
                stage16(wproj + (size_t)(c >> 2) * 512 + k0 + (c & 3) * 8,
                        Bs + g * 512);
            }
            __syncthreads();
            f16x8 af[8], bf[2];
#pragma unroll
            for (int m = 0; m < 8; m++)
                af[m] = *(const f16x8*)&As[(m * 16 + lr) * 32 + lq * 8];
#pragma unroll
            for (int n = 0; n < 2; n++)
                bf[n] = *(const f16x8*)&Bs[(w * 32 + n * 16 + lr) * 32 + lq * 8];
#pragma unroll
            for (int m = 0; m < 8; m++)
#pragma unroll
                for (int n = 0; n < 2; n++)
                    acc[m][n] = __builtin_amdgcn_mfma_f32_16x16x32_f16(af[m], bf[n], acc[m][n], 0, 0, 0);
        }
        // epilogue: x0 -> X (X untouched so far; GLU's first barrier orders vs reads)
#pragma unroll
        for (int n = 0; n < 2; n++) {
            const int col = w * 32 + n * 16 + lr;
            const float t = proj_b[col];
#pragma unroll
            for (int m = 0; m < 8; m++)
#pragma unroll
                for (int j = 0; j < 4; j++)
                    X[(m * 16 + lq * 4 + j) * 264 + col] = (f16)(acc[m][n][j] + t);
        }
    }

    // ---- 4 GLU blocks: C 128x512 (interleaved val/gate), wave cols [w*64,+64), K=256 ----
#pragma unroll 1
    for (int g = 0; g < 4; ++g) {
        f32x4 acc[8][4];
#pragma unroll
        for (int m = 0; m < 8; m++)
#pragma unroll
            for (int n = 0; n < 4; n++) acc[m][n] = (f32x4){0.f, 0.f, 0.f, 0.f};
        const f16* Wg = wglu + (size_t)g * 131072;
        for (int k0 = 0; k0 < 256; k0 += 32) {
            __syncthreads();  // also orders prior X writes vs this step's X reads
#pragma unroll
            for (int i = 0; i < 4; i++) {  // B tile 512x32 = 2048 chunks; 4/wave
                const int g2 = w * 4 + i;
                const int c = g2 * 64 + lane;
                stage16(Wg + (size_t)(c >> 2) * 256 + k0 + (c & 3) * 8,
                        Bs + g2 * 512);
            }
            __syncthreads();
            f16x8 af[8], bf[4];
#pragma unroll
            for (int m = 0; m < 8; m++)
                af[m] = *(const f16x8*)&X[(m * 16 + lr) * 264 + k0 + lq * 8];
#pragma unroll
            for (int n = 0; n < 4; n++)
                bf[n] = *(const f16x8*)&Bs[(w * 64 + n * 16 + lr) * 32 + lq * 8];
#pragma unroll
            for (int m = 0; m < 8; m++)
#pragma unroll
                for (int n = 0; n < 4; n++)
                    acc[m][n] = __builtin_amdgcn_mfma_f32_16x16x32_f16(af[m], bf[n], acc[m][n], 0, 0, 0);
        }
        __syncthreads();  // all waves' X reads done before in-place update
#pragma unroll
        for (int n = 0; n < 4; n++) {
            const int col = w * 64 + n * 16 + lr;
            const float t = t_glu[g * 512 + col];
#pragma unroll
            for (int m = 0; m < 8; m++)
#pragma unroll
                for (int j = 0; j < 4; j++) {
                    float v = acc[m][n][j] + t;
                    float o = __shfl_xor(v, 1, 64);  // val<->gate (adjacent interleaved cols)
                    if (!(lane & 1)) {
                        const int xi = col >> 1;     // in [w*32, w*32+32): owned by this wave
                        const int row = m * 16 + lq * 4 + j;
                        float xn = v * (1.f / (1.f + __expf(-o)));
                        X[row * 264 + xi] = (f16)(xn + (float)X[row * 264 + xi]);
                    }
                }
        }
    }

    // ---- out: C 128x128, wave cols [w*16,+16), K=256; B=wout staged ----
    {
        f32x4 acc[8];
#pragma unroll
        for (int m = 0; m < 8; m++) acc[m] = (f32x4){0.f, 0.f, 0.f, 0.f};
        for (int k0 = 0; k0 < 256; k0 += 32) {
            __syncthreads();  // orders GLU3 X writes vs X reads; guards Bs restage
            {   // B tile 128x32 = 512 chunks; 1/thread
                const int c = tid;
                stage16(wout + (size_t)(c >> 2) * 256 + k0 + (c & 3) * 8,
                        Bs + w * 512);
            }
            __syncthreads();
            f16x8 af[8];
            f16x8 b0 = *(const f16x8*)&Bs[(w * 16 + lr) * 32 + lq * 8];
#pragma unroll
            for (int m = 0; m < 8; m++)
                af[m] = *(const f16x8*)&X[(m * 16 + lr) * 264 + k0 + lq * 8];
#pragma unroll
            for (int m = 0; m < 8; m++)
                acc[m] = __builtin_amdgcn_mfma_f32_16x16x32_f16(af[m], b0, acc[m], 0, 0, 0);
        }
        const int col = w * 16 + lr;
        const float t = out_b[col];
#pragma unroll
        for (int m = 0; m < 8; m++)
#pragma unroll
            for (int j = 0; j < 4; j++)
                outp[(size_t)(rBase + m * 16 + lq * 4 + j) * 128 + col] = acc[m][j] + t;
    }
}

extern "C" void kernel_launch(void* const* d_in, const int* in_sizes, int n_in,
                              void* d_out, int out_size, void* d_ws, size_t ws_size,
                              hipStream_t stream)
{
    const float* inputs    = (const float*)d_in[0];
    const float* priors    = (const float*)d_in[1];
    const float* att_w     = (const float*)d_in[2];
    const float* att_gamma = (const float*)d_in[3];
    const float* att_beta  = (const float*)d_in[4];
    const float* att_mean  = (const float*)d_in[5];
    const float* att_var   = (const float*)d_in[6];
    const float* proj_w    = (const float*)d_in[7];
    const float* proj_b    = (const float*)d_in[8];
    const float* glu_w     = (const float*)d_in[9];
    const float* glu_gamma = (const float*)d_in[10];
    const float* glu_beta  = (const float*)d_in[11];
    const float* glu_mean  = (const float*)d_in[12];
    const float* glu_var   = (const float*)d_in[13];
    const float* out_w     = (const float*)d_in[14];
    const float* out_b     = (const float*)d_in[15];

    char* ws = (char*)d_ws;
    f16*   watt     = (f16*)(ws + 0);          // 512*512 f16
    f16*   wproj    = (f16*)(ws + 524288);     // 256*512
    f16*   wglu     = (f16*)(ws + 786432);     // 4*512*256
    f16*   wout     = (f16*)(ws + 1835008);    // 128*256
    float* t_att    = (float*)(ws + 1900544);  // 512
    float* t_glu    = (float*)(ws + 1902592);  // 4*512
    f16*   inputs16 = (f16*)(ws + 2097152);    // 65536*512 f16 (64MB)
    f16*   maskedb  = (f16*)(ws + 69206016);   // 65536*512 f16

    float* outp  = (float*)d_out;
    float* maskp = outp + (size_t)65536 * 128;
    float* npp   = maskp + (size_t)65536 * 512;

    prep_kernel<<<2048, 256, 0, stream>>>(inputs, att_w, att_gamma, att_beta, att_mean,
                                          att_var, proj_w, glu_w, glu_gamma, glu_beta,
                                          glu_mean, glu_var, out_w, inputs16,
                                          watt, wproj, wglu, wout, t_att, t_glu);

    att_sparsemax_kernel<<<1024, 256, 0, stream>>>(
        inputs16, watt, t_att, priors, maskp, npp, maskedb);

    chain_kernel<<<512, 512, 0, stream>>>(
        maskedb, wproj, proj_b, wglu, t_glu, wout, out_b, outp);
}

// Round 10
// 1045.036 us; speedup vs baseline: 1.6260x; 1.6260x over previous
//
#include <hip/hip_runtime.h>

typedef _Float16 f16;
typedef f16 f16x8 __attribute__((ext_vector_type(8)));
typedef float f32x4 __attribute__((ext_vector_type(4)));

#define EPSBN 1e-3f

// async global->LDS, 16B per lane; lds dest is wave-uniform base (+lane*16 by HW)
__device__ __forceinline__ void stage16(const f16* g, const f16* l) {
    __builtin_amdgcn_global_load_lds(
        (const __attribute__((address_space(1))) unsigned int*)g,
        (__attribute__((address_space(3))) unsigned int*)l,
        16, 0, 0);
}

// Swizzled staging of a [R][32]-f16 K-tile as 16B chunks. LDS slot c holds
// chunk(row=c>>2, kc=(c^(c>>3))&3); involution verified: chunk(row,kc) sits at
// slot row*4 + (kc ^ ((row>>1)&3)). Source stays 64B-coalesced (4 lanes permute
// within one row's 64B); reads spread 8 consecutive rows over 8 slots (2-way, free).
__device__ __forceinline__ void stage_swz(const f16* src, int Ksrc, int k0,
                                          const f16* lds, int g, int lane) {
    const int c = g * 64 + lane;
    const int row = c >> 2;
    const int kc = (c ^ (c >> 3)) & 3;
    stage16(src + (size_t)row * Ksrc + k0 + kc * 8, lds + g * 512);
}
// f16 offset of fragment chunk (row, kc=lq); lrh = (lr>>1)&3 (lane-const)
__device__ __forceinline__ int swz_off(int row, int lq, int lrh) {
    return (row * 4 + (lq ^ lrh)) * 8;
}

// ---------------- prep: fold BN into weights, transpose to [N][K] f16, cvt inputs ----------------
__global__ __launch_bounds__(256) void prep_kernel(
    const float* __restrict__ inputs,
    const float* __restrict__ att_w, const float* __restrict__ att_gamma,
    const float* __restrict__ att_beta, const float* __restrict__ att_mean,
    const float* __restrict__ att_var,
    const float* __restrict__ proj_w,
    const float* __restrict__ glu_w, const float* __restrict__ glu_gamma,
    const float* __restrict__ glu_beta, const float* __restrict__ glu_mean,
    const float* __restrict__ glu_var,
    const float* __restrict__ out_w,
    f16* __restrict__ inputs16,
    f16* __restrict__ watt, f16* __restrict__ wproj, f16* __restrict__ wglu,
    f16* __restrict__ wout, float* __restrict__ t_att, float* __restrict__ t_glu)
{
    int tid = blockIdx.x * blockDim.x + threadIdx.x;
    int nth = gridDim.x * blockDim.x;
    for (int i = tid; i < 65536 * 512 / 8; i += nth) {
        float4 u0 = ((const float4*)inputs)[i * 2];
        float4 u1 = ((const float4*)inputs)[i * 2 + 1];
        f16x8 h = {(f16)u0.x, (f16)u0.y, (f16)u0.z, (f16)u0.w,
                   (f16)u1.x, (f16)u1.y, (f16)u1.z, (f16)u1.w};
        ((f16x8*)inputs16)[i] = h;
    }
    for (int i = tid; i < 512 * 512; i += nth) {
        int n = i >> 9, k = i & 511;
        float s = att_gamma[n] * rsqrtf(att_var[n] + EPSBN);
        watt[i] = (f16)(att_w[k * 512 + n] * s);
    }
    for (int i = tid; i < 256 * 512; i += nth) {
        int n = i >> 9, k = i & 511;
        wproj[i] = (f16)(proj_w[k * 256 + n]);
    }
    for (int i = tid; i < 4 * 512 * 256; i += nth) {
        int g = i >> 17, r = i & 131071;
        int n = r >> 8, k = r & 255;
        int c = (n & 1) ? 256 + (n >> 1) : (n >> 1);
        float s = glu_gamma[g * 512 + c] * rsqrtf(glu_var[g * 512 + c] + EPSBN);
        wglu[i] = (f16)(glu_w[g * 131072 + k * 512 + c] * s);
    }
    for (int i = tid; i < 128 * 256; i += nth) {
        int n = i >> 8, k = i & 255;
        wout[i] = (f16)(out_w[k * 128 + n]);
    }
    for (int n = tid; n < 512; n += nth) {
        float s = att_gamma[n] * rsqrtf(att_var[n] + EPSBN);
        t_att[n] = att_beta[n] - att_mean[n] * s;
    }
    for (int i = tid; i < 4 * 512; i += nth) {
        int g = i >> 9, n = i & 511;
        int c = (n & 1) ? 256 + (n >> 1) : (n >> 1);
        float s = glu_gamma[g * 512 + c] * rsqrtf(glu_var[g * 512 + c] + EPSBN);
        t_glu[i] = glu_beta[g * 512 + c] - glu_mean[g * 512 + c] * s;
    }
}

// ---------------- fused att GEMM + register sparsemax (37.8KB LDS, 4 blocks/CU) ----------------
// 256 threads / 4 waves; block tile 64 rows x 512 cols; wave w: rows w*16..+16, all 512 cols.
// acc[n][j]: row = w*16 + lq*4 + j, col = n*16 + lr. Row r lives on 16 lanes (lq const).
// launch_bounds(256,2): 2nd arg is min waves/EU -> VGPR cap 256 (acc in AGPRs, no spill).
__global__ __launch_bounds__(256, 2) void att_sparsemax_kernel(
    const f16* __restrict__ in16, const f16* __restrict__ watt,
    const float* __restrict__ t_att, const float* __restrict__ priors,
    float* __restrict__ maskout, float* __restrict__ npout,
    f16* __restrict__ masked)
{
    __shared__ f16 Abuf[64 * 32];     // 4KB  A staging (swizzled slots)
    __shared__ f16 Bbuf[64 * 264];    // 33.8KB: B staging (32KB, swizzled) / repack [64][264]
    const int rBase = blockIdx.x * 64;
    const int tid = threadIdx.x;
    const int lane = tid & 63;
    const int w = tid >> 6;
    const int lr = lane & 15, lq = lane >> 4;
    const int lrh = (lr >> 1) & 3;

    f32x4 acc[32];
#pragma unroll
    for (int n = 0; n < 32; n++) acc[n] = (f32x4){0.f, 0.f, 0.f, 0.f};

    const f16* Asrc = in16 + (size_t)rBase * 512;
    for (int k0 = 0; k0 < 512; k0 += 32) {
        __syncthreads();
        stage_swz(Asrc, 512, k0, Abuf, w, lane);            // 64x32: 256 chunks, 1/wave
#pragma unroll
        for (int i = 0; i < 8; i++)                          // 512x32: 2048 chunks, 8/wave
            stage_swz(watt, 512, k0, Bbuf, w * 8 + i, lane);
        __syncthreads();
        f16x8 af = *(const f16x8*)&Abuf[swz_off(w * 16 + lr, lq, lrh)];
#pragma unroll
        for (int n = 0; n < 32; n++) {
            f16x8 bf = *(const f16x8*)&Bbuf[swz_off(n * 16 + lr, lq, lrh)];
            acc[n] = __builtin_amdgcn_mfma_f32_16x16x32_f16(af, bf, acc[n], 0, 0, 0);
        }
    }

    // phase 1: z = (acc + t) * priors, f32 in regs
#pragma unroll
    for (int n = 0; n < 32; n++) {
        const float t = t_att[n * 16 + lr];
        const size_t pb = (size_t)(rBase + w * 16 + lq * 4) * 512 + n * 16 + lr;
#pragma unroll
        for (int j = 0; j < 4; j++)
            acc[n][j] = (acc[n][j] + t) * priors[pb + (size_t)j * 512];
    }

    // phase 2: per-row sparsemax over 16-lane groups (4 rows per group via j)
    float lo[4], hi[4];
#pragma unroll
    for (int j = 0; j < 4; j++) {
        float m = acc[0][j];
#pragma unroll
        for (int n = 1; n < 32; n++) m = fmaxf(m, acc[n][j]);
#pragma unroll
        for (int d = 1; d < 16; d <<= 1) m = fmaxf(m, __shfl_xor(m, d, 64));
        lo[j] = m - 1.f; hi[j] = m;
    }
    for (int it = 0; it < 10; ++it) {
#pragma unroll
        for (int j = 0; j < 4; j++) {
            const float tau = 0.5f * (lo[j] + hi[j]);
            float s = 0.f;
#pragma unroll
            for (int n = 0; n < 32; n++) s += fmaxf(acc[n][j] - tau, 0.f);
#pragma unroll
            for (int d = 1; d < 16; d <<= 1) s += __shfl_xor(s, d, 64);
            if (s >= 1.f) lo[j] = tau; else hi[j] = tau;
        }
    }
    float tau[4];
#pragma unroll
    for (int j = 0; j < 4; j++) {
        float cnt = 0.f, sm = 0.f;
#pragma unroll
        for (int n = 0; n < 32; n++) {
            if (acc[n][j] > lo[j]) { cnt += 1.f; sm += acc[n][j]; }
        }
#pragma unroll
        for (int d = 1; d < 16; d <<= 1) {
            cnt += __shfl_xor(cnt, d, 64);
            sm += __shfl_xor(sm, d, 64);
        }
        tau[j] = (sm - 1.f) / cnt;
    }

    // phase 3: mask into acc; write mask, np (16 lanes x f32 = 64B sectors)
#pragma unroll
    for (int n = 0; n < 32; n++) {
        const size_t pb = (size_t)(rBase + w * 16 + lq * 4) * 512 + n * 16 + lr;
#pragma unroll
        for (int j = 0; j < 4; j++) {
            const float mk = fmaxf(acc[n][j] - tau[j], 0.f);
            acc[n][j] = mk;
            maskout[pb + (size_t)j * 512] = mk;
            npout[pb + (size_t)j * 512] = priors[pb + (size_t)j * 512] * (1.f - mk);
        }
    }

    // phase 4: masked = mask * inputs, via repack in two 256-col halves (reuses Bbuf)
#pragma unroll 1
    for (int h = 0; h < 2; h++) {
        __syncthreads();  // previous reads of Bbuf done
#pragma unroll
        for (int n = 16 * h; n < 16 * h + 16; n++) {
            const int colh = (n - 16 * h) * 16 + lr;
#pragma unroll
            for (int j = 0; j < 4; j++)
                Bbuf[(w * 16 + lq * 4 + j) * 264 + colh] = (f16)acc[n][j];
        }
        __syncthreads();
#pragma unroll
        for (int i = 0; i < 8; i++) {  // 64x256 f16 = 2048 16B-chunks / 256 thr
            const int c = i * 256 + tid;
            const int row = c >> 5, col8 = (c & 31) * 8;
            f16x8 mv = *(const f16x8*)&Bbuf[row * 264 + col8];
            const size_t gb = (size_t)(rBase + row) * 512 + h * 256 + col8;
            f16x8 xv = *(const f16x8*)(in16 + gb);
            *(f16x8*)(masked + gb) = mv * xv;
        }
    }
}

// ---------------- mega-fused feature chain: proj + 4x GLU + out, 2-phase pipelined ----------------
// 512 threads / 8 waves; 128 rows/block; x in LDS [128][264] (in-place GLU update).
// Double-buffered swizzled staging; one barrier per K-step; stages flow across GEMM boundaries.
__global__ __launch_bounds__(512, 2) void chain_kernel(
    const f16* __restrict__ masked, const f16* __restrict__ wproj,
    const float* __restrict__ proj_b, const f16* __restrict__ wglu,
    const float* __restrict__ t_glu, const f16* __restrict__ wout,
    const float* __restrict__ out_b, float* __restrict__ outp)
{
    __shared__ f16 X[128 * 264];      // 67.6KB x buffer
    __shared__ f16 Bs[2][512 * 32];   // 64KB  B staging (swizzled, dbuf)
    __shared__ f16 As[2][128 * 32];   // 16KB  A staging (proj only, swizzled, dbuf)
    const int rBase = blockIdx.x * 128;
    const int tid = threadIdx.x;
    const int lane = tid & 63;
    const int w = tid >> 6;        // 0..7
    const int lr = lane & 15, lq = lane >> 4;
    const int lrh = (lr >> 1) & 3;
    const f16* Asrc = masked + (size_t)rBase * 512;

    // ---- proj: C 128x256, wave cols [w*32,+32), K=512, 16 steps ----
    {
        f32x4 acc[8][2];
#pragma unroll
        for (int m = 0; m < 8; m++)
#pragma unroll
            for (int n = 0; n < 2; n++) acc[m][n] = (f32x4){0.f, 0.f, 0.f, 0.f};
        // prologue: tile 0 into buf 0
        stage_swz(Asrc, 512, 0, As[0], w, lane);                 // 128x32: 512 chunks, 1/wave
#pragma unroll
        for (int i = 0; i < 2; i++)
            stage_swz(wproj, 512, 0, Bs[0], w * 2 + i, lane);    // 256x32: 1024 chunks, 2/wave
        __syncthreads();
        for (int k = 0; k < 16; k++) {
            const int cur = k & 1;
            if (k + 1 < 16) {
                stage_swz(Asrc, 512, (k + 1) * 32, As[cur ^ 1], w, lane);
#pragma unroll
                for (int i = 0; i < 2; i++)
                    stage_swz(wproj, 512, (k + 1) * 32, Bs[cur ^ 1], w * 2 + i, lane);
            } else {  // stage GLU0 tile 0 into Bs[0] (cur=1 at k=15)
#pragma unroll
                for (int i = 0; i < 4; i++)
                    stage_swz(wglu, 256, 0, Bs[0], w * 4 + i, lane);
            }
            f16x8 af[8], bf[2];
#pragma unroll
            for (int m = 0; m < 8; m++)
                af[m] = *(const f16x8*)&As[cur][swz_off(m * 16 + lr, lq, lrh)];
#pragma unroll
            for (int n = 0; n < 2; n++)
                bf[n] = *(const f16x8*)&Bs[cur][swz_off(w * 32 + n * 16 + lr, lq, lrh)];
#pragma unroll
            for (int m = 0; m < 8; m++)
#pragma unroll
                for (int n = 0; n < 2; n++)
                    acc[m][n] = __builtin_amdgcn_mfma_f32_16x16x32_f16(af[m], bf[n], acc[m][n], 0, 0, 0);
            __syncthreads();
        }
        // epilogue: x0 -> X (first touch of X; next barrier orders vs GLU reads)
#pragma unroll
        for (int n = 0; n < 2; n++) {
            const int col = w * 32 + n * 16 + lr;
            const float t = proj_b[col];
#pragma unroll
            for (int m = 0; m < 8; m++)
#pragma unroll
                for (int j = 0; j < 4; j++)
                    X[(m * 16 + lq * 4 + j) * 264 + col] = (f16)(acc[m][n][j] + t);
        }
    }

    // ---- 4 GLU blocks: C 128x512 (interleaved val/gate), wave cols [w*64,+64), K=256, 8 steps ----
#pragma unroll 1
    for (int g = 0; g < 4; ++g) {
        f32x4 acc[8][4];
#pragma unroll
        for (int m = 0; m < 8; m++)
#pragma unroll
            for (int n = 0; n < 4; n++) acc[m][n] = (f32x4){0.f, 0.f, 0.f, 0.f};
        const f16* Wg = wglu + (size_t)g * 131072;
        __syncthreads();  // orders X writes; drains tile-0 stage (issued in prev loop)
        for (int k = 0; k < 8; k++) {
            const int cur = k & 1;
            if (k + 1 < 8) {
#pragma unroll
                for (int i = 0; i < 4; i++)                      // 512x32: 2048 chunks, 4/wave
                    stage_swz(Wg, 256, (k + 1) * 32, Bs[cur ^ 1], w * 4 + i, lane);
            } else if (g < 3) {
#pragma unroll
                for (int i = 0; i < 4; i++)
                    stage_swz(wglu + (size_t)(g + 1) * 131072, 256, 0, Bs[0], w * 4 + i, lane);
            } else {
                stage_swz(wout, 256, 0, Bs[0], w, lane);         // 128x32: 512 chunks, 1/wave
            }
            f16x8 af[8], bf[4];
#pragma unroll
            for (int m = 0; m < 8; m++)
                af[m] = *(const f16x8*)&X[(m * 16 + lr) * 264 + k * 32 + lq * 8];
#pragma unroll
            for (int n = 0; n < 4; n++)
                bf[n] = *(const f16x8*)&Bs[cur][swz_off(w * 64 + n * 16 + lr, lq, lrh)];
#pragma unroll
            for (int m = 0; m < 8; m++)
#pragma unroll
                for (int n = 0; n < 4; n++)
                    acc[m][n] = __builtin_amdgcn_mfma_f32_16x16x32_f16(af[m], bf[n], acc[m][n], 0, 0, 0);
            __syncthreads();
        }
        // in-place X update (all waves' X reads done at last barrier)
#pragma unroll
        for (int n = 0; n < 4; n++) {
            const int col = w * 64 + n * 16 + lr;
            const float t = t_glu[g * 512 + col];
#pragma unroll
            for (int m = 0; m < 8; m++)
#pragma unroll
                for (int j = 0; j < 4; j++) {
                    float v = acc[m][n][j] + t;
                    float o = __shfl_xor(v, 1, 64);  // val<->gate (adjacent interleaved cols)
                    if (!(lane & 1)) {
                        const int xi = col >> 1;
                        const int row = m * 16 + lq * 4 + j;
                        float xn = v * (1.f / (1.f + __expf(-o)));
                        X[row * 264 + xi] = (f16)(xn + (float)X[row * 264 + xi]);
                    }
                }
        }
    }

    // ---- out: C 128x128, wave cols [w*16,+16), K=256, 8 steps ----
    {
        f32x4 acc[8];
#pragma unroll
        for (int m = 0; m < 8; m++) acc[m] = (f32x4){0.f, 0.f, 0.f, 0.f};
        __syncthreads();  // orders GLU3 X writes (out tile 0 staged+drained in GLU3 loop)
        for (int k = 0; k < 8; k++) {
            const int cur = k & 1;
            if (k + 1 < 8)
                stage_swz(wout, 256, (k + 1) * 32, Bs[cur ^ 1], w, lane);
            f16x8 af[8];
            f16x8 b0 = *(const f16x8*)&Bs[cur][swz_off(w * 16 + lr, lq, lrh)];
#pragma unroll
            for (int m = 0; m < 8; m++)
                af[m] = *(const f16x8*)&X[(m * 16 + lr) * 264 + k * 32 + lq * 8];
#pragma unroll
            for (int m = 0; m < 8; m++)
                acc[m] = __builtin_amdgcn_mfma_f32_16x16x32_f16(af[m], b0, acc[m], 0, 0, 0);
            __syncthreads();
        }
        const int col = w * 16 + lr;
        const float t = out_b[col];
#pragma unroll
        for (int m = 0; m < 8; m++)
#pragma unroll
            for (int j = 0; j < 4; j++)
                outp[(size_t)(rBase + m * 16 + lq * 4 + j) * 128 + col] = acc[m][j] + t;
    }
}

extern "C" void kernel_launch(void* const* d_in, const int* in_sizes, int n_in,
                              void* d_out, int out_size, void* d_ws, size_t ws_size,
                              hipStream_t stream)
{
    const float* inputs    = (const float*)d_in[0];
    const float* priors    = (const float*)d_in[1];
    const float* att_w     = (const float*)d_in[2];
    const float* att_gamma = (const float*)d_in[3];
    const float* att_beta  = (const float*)d_in[4];
    const float* att_mean  = (const float*)d_in[5];
    const float* att_var   = (const float*)d_in[6];
    const float* proj_w    = (const float*)d_in[7];
    const float* proj_b    = (const float*)d_in[8];
    const float* glu_w     = (const float*)d_in[9];
    const float* glu_gamma = (const float*)d_in[10];
    const float* glu_beta  = (const float*)d_in[11];
    const float* glu_mean  = (const float*)d_in[12];
    const float* glu_var   = (const float*)d_in[13];
    const float* out_w     = (const float*)d_in[14];
    const float* out_b     = (const float*)d_in[15];

    char* ws = (char*)d_ws;
    f16*   watt     = (f16*)(ws + 0);          // 512*512 f16
    f16*   wproj    = (f16*)(ws + 524288);     // 256*512
    f16*   wglu     = (f16*)(ws + 786432);     // 4*512*256
    f16*   wout     = (f16*)(ws + 1835008);    // 128*256
    float* t_att    = (float*)(ws + 1900544);  // 512
    float* t_glu    = (float*)(ws + 1902592);  // 4*512
    f16*   inputs16 = (f16*)(ws + 2097152);    // 65536*512 f16 (64MB)
    f16*   maskedb  = (f16*)(ws + 69206016);   // 65536*512 f16

    float* outp  = (float*)d_out;
    float* maskp = outp + (size_t)65536 * 128;
    float* npp   = maskp + (size_t)65536 * 512;

    prep_kernel<<<2048, 256, 0, stream>>>(inputs, att_w, att_gamma, att_beta, att_mean,
                                          att_var, proj_w, glu_w, glu_gamma, glu_beta,
                                          glu_mean, glu_var, out_w, inputs16,
                                          watt, wproj, wglu, wout, t_att, t_glu);

    att_sparsemax_kernel<<<1024, 256, 0, stream>>>(
        inputs16, watt, t_att, priors, maskp, npp, maskedb);

    chain_kernel<<<512, 512, 0, stream>>>(
        maskedb, wproj, proj_b, wglu, t_glu, wout, out_b, outp);
}

// Round 11
// 456.357 us; speedup vs baseline: 3.7235x; 2.2900x over previous
//
#include <hip/hip_runtime.h>

typedef _Float16 f16;
typedef f16 f16x8 __attribute__((ext_vector_type(8)));
typedef float f32x4 __attribute__((ext_vector_type(4)));

#define EPSBN 1e-3f

// async global->LDS, 16B per lane; lds dest is wave-uniform base (+lane*16 by HW)
__device__ __forceinline__ void stage16(const f16* g, const f16* l) {
    __builtin_amdgcn_global_load_lds(
        (const __attribute__((address_space(1))) unsigned int*)g,
        (__attribute__((address_space(3))) unsigned int*)l,
        16, 0, 0);
}

// Swizzled staging of a [R][32]-f16 K-tile as 16B chunks. LDS slot c holds
// chunk(row=c>>2, kc=(c^(c>>3))&3); chunk(row,kc) sits at slot row*4+(kc^((row>>1)&3)).
// Source stays 64B-coalesced; fragment reads spread 8 rows over 8 slots (2-way, free).
__device__ __forceinline__ void stage_swz(const f16* src, int Ksrc, int k0,
                                          const f16* lds, int g, int lane) {
    const int c = g * 64 + lane;
    const int row = c >> 2;
    const int kc = (c ^ (c >> 3)) & 3;
    stage16(src + (size_t)row * Ksrc + k0 + kc * 8, lds + g * 512);
}
// f16 offset of fragment chunk (row, kc=lq); lrh = (lr>>1)&3 (lane-const)
__device__ __forceinline__ int swz_off(int row, int lq, int lrh) {
    return (row * 4 + (lq ^ lrh)) * 8;
}

// ---------------- prep: fold BN into weights, transpose to [N][K] f16, cvt inputs ----------------
__global__ __launch_bounds__(256) void prep_kernel(
    const float* __restrict__ inputs,
    const float* __restrict__ att_w, const float* __restrict__ att_gamma,
    const float* __restrict__ att_beta, const float* __restrict__ att_mean,
    const float* __restrict__ att_var,
    const float* __restrict__ proj_w,
    const float* __restrict__ glu_w, const float* __restrict__ glu_gamma,
    const float* __restrict__ glu_beta, const float* __restrict__ glu_mean,
    const float* __restrict__ glu_var,
    const float* __restrict__ out_w,
    f16* __restrict__ inputs16,
    f16* __restrict__ watt, f16* __restrict__ wproj, f16* __restrict__ wglu,
    f16* __restrict__ wout, float* __restrict__ t_att, float* __restrict__ t_glu)
{
    int tid = blockIdx.x * blockDim.x + threadIdx.x;
    int nth = gridDim.x * blockDim.x;
    for (int i = tid; i < 65536 * 512 / 8; i += nth) {
        float4 u0 = ((const float4*)inputs)[i * 2];
        float4 u1 = ((const float4*)inputs)[i * 2 + 1];
        f16x8 h = {(f16)u0.x, (f16)u0.y, (f16)u0.z, (f16)u0.w,
                   (f16)u1.x, (f16)u1.y, (f16)u1.z, (f16)u1.w};
        ((f16x8*)inputs16)[i] = h;
    }
    for (int i = tid; i < 512 * 512; i += nth) {
        int n = i >> 9, k = i & 511;
        float s = att_gamma[n] * rsqrtf(att_var[n] + EPSBN);
        watt[i] = (f16)(att_w[k * 512 + n] * s);
    }
    for (int i = tid; i < 256 * 512; i += nth) {
        int n = i >> 9, k = i & 511;
        wproj[i] = (f16)(proj_w[k * 256 + n]);
    }
    for (int i = tid; i < 4 * 512 * 256; i += nth) {
        int g = i >> 17, r = i & 131071;
        int n = r >> 8, k = r & 255;
        int c = (n & 1) ? 256 + (n >> 1) : (n >> 1);
        float s = glu_gamma[g * 512 + c] * rsqrtf(glu_var[g * 512 + c] + EPSBN);
        wglu[i] = (f16)(glu_w[g * 131072 + k * 512 + c] * s);
    }
    for (int i = tid; i < 128 * 256; i += nth) {
        int n = i >> 8, k = i & 255;
        wout[i] = (f16)(out_w[k * 128 + n]);
    }
    for (int n = tid; n < 512; n += nth) {
        float s = att_gamma[n] * rsqrtf(att_var[n] + EPSBN);
        t_att[n] = att_beta[n] - att_mean[n] * s;
    }
    for (int i = tid; i < 4 * 512; i += nth) {
        int g = i >> 9, n = i & 511;
        int c = (n & 1) ? 256 + (n >> 1) : (n >> 1);
        float s = glu_gamma[g * 512 + c] * rsqrtf(glu_var[g * 512 + c] + EPSBN);
        t_glu[i] = glu_beta[g * 512 + c] - glu_mean[g * 512 + c] * s;
    }
}

// ---------------- fused att GEMM + register sparsemax (72KB LDS, dbuf pipeline) ----------------
// 256 threads / 4 waves; block tile 64 rows x 512 cols; wave w: rows w*16..+16, all 512 cols.
// acc[n][j]: row = w*16 + lq*4 + j, col = n*16 + lr. Row r lives on 16 lanes (lq const).
// launch_bounds(256,2): min 2 waves/EU -> VGPR cap 256; acc in AGPRs, NO runtime acc indexing.
__global__ __launch_bounds__(256, 2) void att_sparsemax_kernel(
    const f16* __restrict__ in16, const f16* __restrict__ watt,
    const float* __restrict__ t_att, const float* __restrict__ priors,
    float* __restrict__ maskout, float* __restrict__ npout,
    f16* __restrict__ masked)
{
    __shared__ f16 Abuf[2 * 2048];    // 2 x 4KB A staging (swizzled)
    __shared__ f16 Bbuf[2 * 16384];   // 2 x 32KB B staging (swizzled); front 33.8KB = repack [64][264]
    const int rBase = blockIdx.x * 64;
    const int tid = threadIdx.x;
    const int lane = tid & 63;
    const int w = tid >> 6;
    const int lr = lane & 15, lq = lane >> 4;
    const int lrh = (lr >> 1) & 3;

    f32x4 acc[32];
#pragma unroll
    for (int n = 0; n < 32; n++) acc[n] = (f32x4){0.f, 0.f, 0.f, 0.f};

    const f16* Asrc = in16 + (size_t)rBase * 512;
    // prologue: tile 0 -> buf 0
    stage_swz(Asrc, 512, 0, Abuf, w, lane);                    // 64x32: 256 chunks, 1/wave
#pragma unroll
    for (int i = 0; i < 8; i++)                                 // 512x32: 2048 chunks, 8/wave
        stage_swz(watt, 512, 0, Bbuf, w * 8 + i, lane);
    __syncthreads();
    for (int k = 0; k < 16; k++) {
        const int cur = k & 1;
        if (k + 1 < 16) {  // prefetch next tile into other buffer (read-free since last barrier)
            stage_swz(Asrc, 512, (k + 1) * 32, Abuf + (cur ^ 1) * 2048, w, lane);
#pragma unroll
            for (int i = 0; i < 8; i++)
                stage_swz(watt, 512, (k + 1) * 32, Bbuf + (cur ^ 1) * 16384, w * 8 + i, lane);
        }
        f16x8 af = *(const f16x8*)&Abuf[cur * 2048 + swz_off(w * 16 + lr, lq, lrh)];
#pragma unroll
        for (int n = 0; n < 32; n++) {
            f16x8 bf = *(const f16x8*)&Bbuf[cur * 16384 + swz_off(n * 16 + lr, lq, lrh)];
            acc[n] = __builtin_amdgcn_mfma_f32_16x16x32_f16(af, bf, acc[n], 0, 0, 0);
        }
        __syncthreads();  // drains this step's loads (vmcnt0 before barrier) + guards buffers
    }

    // phase 1: z = (acc + t) * priors, f32 in regs
#pragma unroll
    for (int n = 0; n < 32; n++) {
        const float t = t_att[n * 16 + lr];
        const size_t pb = (size_t)(rBase + w * 16 + lq * 4) * 512 + n * 16 + lr;
#pragma unroll
        for (int j = 0; j < 4; j++)
            acc[n][j] = (acc[n][j] + t) * priors[pb + (size_t)j * 512];
    }

    // phase 2: per-row sparsemax over 16-lane groups (4 rows per group via j)
    float lo[4], hi[4];
#pragma unroll
    for (int j = 0; j < 4; j++) {
        float m = acc[0][j];
#pragma unroll
        for (int n = 1; n < 32; n++) m = fmaxf(m, acc[n][j]);
#pragma unroll
        for (int d = 1; d < 16; d <<= 1) m = fmaxf(m, __shfl_xor(m, d, 64));
        lo[j] = m - 1.f; hi[j] = m;
    }
    for (int it = 0; it < 10; ++it) {
#pragma unroll
        for (int j = 0; j < 4; j++) {
            const float tau = 0.5f * (lo[j] + hi[j]);
            float s = 0.f;
#pragma unroll
            for (int n = 0; n < 32; n++) s += fmaxf(acc[n][j] - tau, 0.f);
#pragma unroll
            for (int d = 1; d < 16; d <<= 1) s += __shfl_xor(s, d, 64);
            if (s >= 1.f) lo[j] = tau; else hi[j] = tau;
        }
    }
    float tau[4];
#pragma unroll
    for (int j = 0; j < 4; j++) {
        float cnt = 0.f, sm = 0.f;
#pragma unroll
        for (int n = 0; n < 32; n++) {
            if (acc[n][j] > lo[j]) { cnt += 1.f; sm += acc[n][j]; }
        }
#pragma unroll
        for (int d = 1; d < 16; d <<= 1) {
            cnt += __shfl_xor(cnt, d, 64);
            sm += __shfl_xor(sm, d, 64);
        }
        tau[j] = (sm - 1.f) / cnt;
    }

    // phase 3: mask into acc; write mask, np (16 lanes x f32 = 64B sectors)
#pragma unroll
    for (int n = 0; n < 32; n++) {
        const size_t pb = (size_t)(rBase + w * 16 + lq * 4) * 512 + n * 16 + lr;
#pragma unroll
        for (int j = 0; j < 4; j++) {
            const float mk = fmaxf(acc[n][j] - tau[j], 0.f);
            acc[n][j] = mk;
            maskout[pb + (size_t)j * 512] = mk;
            npout[pb + (size_t)j * 512] = priors[pb + (size_t)j * 512] * (1.f - mk);
        }
    }

    // phase 4: masked = mask * inputs via repack; FULLY UNROLLED h -> acc indices static (rule #20)
#pragma unroll
    for (int h = 0; h < 2; h++) {
        if (h) __syncthreads();  // h=0 guarded by K-loop's final barrier
#pragma unroll
        for (int i = 0; i < 16; i++) {
            const int n = h * 16 + i;       // compile-time constant
            const int colh = i * 16 + lr;
#pragma unroll
            for (int j = 0; j < 4; j++)
                Bbuf[(w * 16 + lq * 4 + j) * 264 + colh] = (f16)acc[n][j];
        }
        __syncthreads();
#pragma unroll
        for (int i = 0; i < 8; i++) {  // 64x256 f16 = 2048 16B-chunks / 256 thr
            const int c = i * 256 + tid;
            const int row = c >> 5, col8 = (c & 31) * 8;
            f16x8 mv = *(const f16x8*)&Bbuf[row * 264 + col8];
            const size_t gb = (size_t)(rBase + row) * 512 + h * 256 + col8;
            f16x8 xv = *(const f16x8*)(in16 + gb);
            *(f16x8*)(masked + gb) = mv * xv;
        }
    }
}

// ---------------- mega-fused feature chain: proj + 4x GLU + out, 2-phase pipelined ----------------
// 512 threads / 8 waves; 128 rows/block; x in LDS [128][264] (in-place GLU update).
// Double-buffered swizzled staging; one barrier per K-step; stages flow across GEMM boundaries.
__global__ __launch_bounds__(512, 2) void chain_kernel(
    const f16* __restrict__ masked, const f16* __restrict__ wproj,
    const float* __restrict__ proj_b, const f16* __restrict__ wglu,
    const float* __restrict__ t_glu, const f16* __restrict__ wout,
    const float* __restrict__ out_b, float* __restrict__ outp)
{
    __shared__ f16 X[128 * 264];      // 67.6KB x buffer
    __shared__ f16 Bs[2][512 * 32];   // 64KB  B staging (swizzled, dbuf)
    __shared__ f16 As[2][128 * 32];   // 16KB  A staging (proj only, swizzled, dbuf)
    const int rBase = blockIdx.x * 128;
    const int tid = threadIdx.x;
    const int lane = tid & 63;
    const int w = tid >> 6;        // 0..7
    const int lr = lane & 15, lq = lane >> 4;
    const int lrh = (lr >> 1) & 3;
    const f16* Asrc = masked + (size_t)rBase * 512;

    // ---- proj: C 128x256, wave cols [w*32,+32), K=512, 16 steps ----
    {
        f32x4 acc[8][2];
#pragma unroll
        for (int m = 0; m < 8; m++)
#pragma unroll
            for (int n = 0; n < 2; n++) acc[m][n] = (f32x4){0.f, 0.f, 0.f, 0.f};
        stage_swz(Asrc, 512, 0, As[0], w, lane);
#pragma unroll
        for (int i = 0; i < 2; i++)
            stage_swz(wproj, 512, 0, Bs[0], w * 2 + i, lane);
        __syncthreads();
        for (int k = 0; k < 16; k++) {
            const int cur = k & 1;
            if (k + 1 < 16) {
                stage_swz(Asrc, 512, (k + 1) * 32, As[cur ^ 1], w, lane);
#pragma unroll
                for (int i = 0; i < 2; i++)
                    stage_swz(wproj, 512, (k + 1) * 32, Bs[cur ^ 1], w * 2 + i, lane);
            } else {  // stage GLU0 tile 0 into Bs[0] (cur=1 at k=15)
#pragma unroll
                for (int i = 0; i < 4; i++)
                    stage_swz(wglu, 256, 0, Bs[0], w * 4 + i, lane);
            }
            f16x8 af[8], bf[2];
#pragma unroll
            for (int m = 0; m < 8; m++)
                af[m] = *(const f16x8*)&As[cur][swz_off(m * 16 + lr, lq, lrh)];
#pragma unroll
            for (int n = 0; n < 2; n++)
                bf[n] = *(const f16x8*)&Bs[cur][swz_off(w * 32 + n * 16 + lr, lq, lrh)];
#pragma unroll
            for (int m = 0; m < 8; m++)
#pragma unroll
                for (int n = 0; n < 2; n++)
                    acc[m][n] = __builtin_amdgcn_mfma_f32_16x16x32_f16(af[m], bf[n], acc[m][n], 0, 0, 0);
            __syncthreads();
        }
#pragma unroll
        for (int n = 0; n < 2; n++) {
            const int col = w * 32 + n * 16 + lr;
            const float t = proj_b[col];
#pragma unroll
            for (int m = 0; m < 8; m++)
#pragma unroll
                for (int j = 0; j < 4; j++)
                    X[(m * 16 + lq * 4 + j) * 264 + col] = (f16)(acc[m][n][j] + t);
        }
    }

    // ---- 4 GLU blocks: C 128x512 (interleaved val/gate), wave cols [w*64,+64), K=256, 8 steps ----
#pragma unroll 1
    for (int g = 0; g < 4; ++g) {
        f32x4 acc[8][4];
#pragma unroll
        for (int m = 0; m < 8; m++)
#pragma unroll
            for (int n = 0; n < 4; n++) acc[m][n] = (f32x4){0.f, 0.f, 0.f, 0.f};
        const f16* Wg = wglu + (size_t)g * 131072;
        __syncthreads();  // orders X writes; tile-0 stage drained by prev loop's last barrier
        for (int k = 0; k < 8; k++) {
            const int cur = k & 1;
            if (k + 1 < 8) {
#pragma unroll
                for (int i = 0; i < 4; i++)
                    stage_swz(Wg, 256, (k + 1) * 32, Bs[cur ^ 1], w * 4 + i, lane);
            } else if (g < 3) {
#pragma unroll
                for (int i = 0; i < 4; i++)
                    stage_swz(wglu + (size_t)(g + 1) * 131072, 256, 0, Bs[0], w * 4 + i, lane);
            } else {
                stage_swz(wout, 256, 0, Bs[0], w, lane);
            }
            f16x8 af[8], bf[4];
#pragma unroll
            for (int m = 0; m < 8; m++)
                af[m] = *(const f16x8*)&X[(m * 16 + lr) * 264 + k * 32 + lq * 8];
#pragma unroll
            for (int n = 0; n < 4; n++)
                bf[n] = *(const f16x8*)&Bs[cur][swz_off(w * 64 + n * 16 + lr, lq, lrh)];
#pragma unroll
            for (int m = 0; m < 8; m++)
#pragma unroll
                for (int n = 0; n < 4; n++)
                    acc[m][n] = __builtin_amdgcn_mfma_f32_16x16x32_f16(af[m], bf[n], acc[m][n], 0, 0, 0);
            __syncthreads();
        }
#pragma unroll
        for (int n = 0; n < 4; n++) {
            const int col = w * 64 + n * 16 + lr;
            const float t = t_glu[g * 512 + col];
#pragma unroll
            for (int m = 0; m < 8; m++)
#pragma unroll
                for (int j = 0; j < 4; j++) {
                    float v = acc[m][n][j] + t;
                    float o = __shfl_xor(v, 1, 64);  // val<->gate (adjacent interleaved cols)
                    if (!(lane & 1)) {
                        const int xi = col >> 1;
                        const int row = m * 16 + lq * 4 + j;
                        float xn = v * (1.f / (1.f + __expf(-o)));
                        X[row * 264 + xi] = (f16)(xn + (float)X[row * 264 + xi]);
                    }
                }
        }
    }

    // ---- out: C 128x128, wave cols [w*16,+16), K=256, 8 steps ----
    {
        f32x4 acc[8];
#pragma unroll
        for (int m = 0; m < 8; m++) acc[m] = (f32x4){0.f, 0.f, 0.f, 0.f};
        __syncthreads();  // orders GLU3 X writes (out tile 0 staged in GLU3 loop)
        for (int k = 0; k < 8; k++) {
            const int cur = k & 1;
            if (k + 1 < 8)
                stage_swz(wout, 256, (k + 1) * 32, Bs[cur ^ 1], w, lane);
            f16x8 af[8];
            f16x8 b0 = *(const f16x8*)&Bs[cur][swz_off(w * 16 + lr, lq, lrh)];
#pragma unroll
            for (int m = 0; m < 8; m++)
                af[m] = *(const f16x8*)&X[(m * 16 + lr) * 264 + k * 32 + lq * 8];
#pragma unroll
            for (int m = 0; m < 8; m++)
                acc[m] = __builtin_amdgcn_mfma_f32_16x16x32_f16(af[m], b0, acc[m], 0, 0, 0);
            __syncthreads();
        }
        const int col = w * 16 + lr;
        const float t = out_b[col];
#pragma unroll
        for (int m = 0; m < 8; m++)
#pragma unroll
            for (int j = 0; j < 4; j++)
                outp[(size_t)(rBase + m * 16 + lq * 4 + j) * 128 + col] = acc[m][j] + t;
    }
}

extern "C" void kernel_launch(void* const* d_in, const int* in_sizes, int n_in,
                              void* d_out, int out_size, void* d_ws, size_t ws_size,
                              hipStream_t stream)
{
    const float* inputs    = (const float*)d_in[0];
    const float* priors    = (const float*)d_in[1];
    const float* att_w     = (const float*)d_in[2];
    const float* att_gamma = (const float*)d_in[3];
    const float* att_beta  = (const float*)d_in[4];
    const float* att_mean  = (const float*)d_in[5];
    const float* att_var   = (const float*)d_in[6];
    const float* proj_w    = (const float*)d_in[7];
    const float* proj_b    = (const float*)d_in[8];
    const float* glu_w     = (const float*)d_in[9];
    const float* glu_gamma = (const float*)d_in[10];
    const float* glu_beta  = (const float*)d_in[11];
    const float* glu_mean  = (const float*)d_in[12];
    const float* glu_var   = (const float*)d_in[13];
    const float* out_w     = (const float*)d_in[14];
    const float* out_b     = (const float*)d_in[15];

    char* ws = (char*)d_ws;
    f16*   watt     = (f16*)(ws + 0);          // 512*512 f16
    f16*   wproj    = (f16*)(ws + 524288);     // 256*512
    f16*   wglu     = (f16*)(ws + 786432);     // 4*512*256
    f16*   wout     = (f16*)(ws + 1835008);    // 128*256
    float* t_att    = (float*)(ws + 1900544);  // 512
    float* t_glu    = (float*)(ws + 1902592);  // 4*512
    f16*   inputs16 = (f16*)(ws + 2097152);    // 65536*512 f16 (64MB)
    f16*   maskedb  = (f16*)(ws + 69206016);   // 65536*512 f16

    float* outp  = (float*)d_out;
    float* maskp = outp + (size_t)65536 * 128;
    float* npp   = maskp + (size_t)65536 * 512;

    prep_kernel<<<2048, 256, 0, stream>>>(inputs, att_w, att_gamma, att_beta, att_mean,
                                          att_var, proj_w, glu_w, glu_gamma, glu_beta,
                                          glu_mean, glu_var, out_w, inputs16,
                                          watt, wproj, wglu, wout, t_att, t_glu);

    att_sparsemax_kernel<<<1024, 256, 0, stream>>>(
        inputs16, watt, t_att, priors, maskp, npp, maskedb);

    chain_kernel<<<512, 512, 0, stream>>>(
        maskedb, wproj, proj_b, wglu, t_glu, wout, out_b, outp);
}